// Round 6
// baseline (509.012 us; speedup 1.0000x reference)
//
#include <hip/hip_runtime.h>
#include <hip/hip_bf16.h>

typedef __bf16 bf16x8 __attribute__((ext_vector_type(8)));
typedef float f32x4 __attribute__((ext_vector_type(4)));

__device__ __forceinline__ void gload16(const void* g, void* l) {
  __builtin_amdgcn_global_load_lds(
      (const __attribute__((address_space(1))) unsigned int*)g,
      (__attribute__((address_space(3))) unsigned int*)l, 16, 0, 0);
}

__device__ __forceinline__ float gelu_f(float x) {
  return 0.5f * x * (1.f + erff(x * 0.70710678118654752f));
}
__device__ __forceinline__ float sigmoid_f(float x) {
  return 1.f / (1.f + __expf(-x));
}

// ---------------------------------------------------------------------------
// 8-wave 256x256 deep-pipelined GEMM (T3+T4+T5): BK=32, 4 LDS buffers
// (128 KiB dynamic), prefetch depth 3, counted vmcnt(8) (never 0 in loop).
// EPI: 0 = bias+bf16, 2 = gate fusion -> bf16 U.
// ---------------------------------------------------------------------------
template<int EPI>
__global__ __launch_bounds__(512, 2)
void gemm8_kernel(const __hip_bfloat16* __restrict__ A0, int lda0,
                  const __hip_bfloat16* __restrict__ A1, int lda1,
                  const __hip_bfloat16* __restrict__ A2, int lda2,
                  int ks1, int ks2,
                  const __hip_bfloat16* __restrict__ B, int ldb,
                  const float* __restrict__ bias,
                  const float* __restrict__ fvec,
                  const float* __restrict__ flags,
                  void* __restrict__ C, int ldc, int K)
{
  extern __shared__ __align__(16) char lds[];
  const int t = threadIdx.x;
  const int l = t & 63;
  const int w = t >> 6;
  const int l15 = l & 15, lg = (l >> 4) & 3;
  const int orig = blockIdx.y * gridDim.x + blockIdx.x;
  const int nwg = gridDim.x * gridDim.y;
  const int gy = gridDim.y;
  const int xcd = orig & 7, rk = orig >> 3, q = nwg >> 3, r = nwg & 7;
  const int bid = (xcd < r ? xcd * (q + 1) : r * (q + 1) + (xcd - r) * q) + rk;
  const int m0 = (bid % gy) * 256;
  const int n0 = (bid / gy) * 256;

  const int srow = t >> 2;
  const int kc8 = ((t & 3) ^ ((t >> 3) & 3)) * 8;
  const int mbase = (w >> 2) * 128;
  const int nbase = (w & 3) * 64;
  const int swz = (l15 >> 1) & 3;
  const int kslot = (lg ^ swz) * 8;
  int aoff[8], boff[4];
#pragma unroll
  for (int mf = 0; mf < 8; ++mf) aoff[mf] = (mbase + mf * 16 + l15) * 32 + kslot;
#pragma unroll
  for (int nf = 0; nf < 4; ++nf) boff[nf] = (nbase + nf * 16 + l15) * 32 + kslot;

  auto segA = [&](int k0, const __hip_bfloat16*& Ap, int& ldA, int& krel) {
    if (k0 >= ks2)      { Ap = A2; ldA = lda2; krel = k0 - ks2; }
    else if (k0 >= ks1) { Ap = A1; ldA = lda1; krel = k0 - ks1; }
    else                { Ap = A0; ldA = lda0; krel = k0; }
  };
  auto stageA = [&](int buf, const __hip_bfloat16* Ap, int ldA, int krel) {
    char* base = lds + buf * 32768 + t * 16;
    gload16(Ap + (size_t)(m0 + srow) * ldA + krel + kc8, base);
    gload16(Ap + (size_t)(m0 + 128 + srow) * ldA + krel + kc8, base + 8192);
  };
  auto stageB = [&](int buf, int k0) {
    char* base = lds + buf * 32768 + 16384 + t * 16;
    gload16(B + (size_t)(n0 + srow) * ldb + k0 + kc8, base);
    gload16(B + (size_t)(n0 + 128 + srow) * ldb + k0 + kc8, base + 8192);
  };

  f32x4 acc[8][4] = {};
  const int NT = K >> 5;

#pragma unroll 1
  for (int pt = 0; pt < 3; ++pt) {
    const __hip_bfloat16* Ap; int ldA, krel;
    segA(pt * 32, Ap, ldA, krel);
    stageA(pt, Ap, ldA, krel);
    stageB(pt, pt * 32);
  }
  asm volatile("s_waitcnt vmcnt(8)" ::: "memory");
  __builtin_amdgcn_s_barrier();
  __builtin_amdgcn_sched_barrier(0);

#pragma unroll 1
  for (int tt = 0; tt < NT; ++tt) {
    const int buf = tt & 3;
    const __hip_bfloat16* As = (const __hip_bfloat16*)(lds + buf * 32768);
    const __hip_bfloat16* Bs = (const __hip_bfloat16*)(lds + buf * 32768 + 16384);
    const int pf = tt + 3;
    const bool do_pf = pf < NT;
    const int pbuf = pf & 3;
    const __hip_bfloat16* Ap = A0; int ldA = lda0, krel = 0;
    if (do_pf) segA(pf * 32, Ap, ldA, krel);

    bf16x8 bv[4], av[4];
#pragma unroll
    for (int nf = 0; nf < 4; ++nf) bv[nf] = *(const bf16x8*)(Bs + boff[nf]);
#pragma unroll
    for (int mf = 0; mf < 4; ++mf) av[mf] = *(const bf16x8*)(As + aoff[mf]);
    if (do_pf) stageA(pbuf, Ap, ldA, krel);
    __builtin_amdgcn_s_setprio(1);
#pragma unroll
    for (int mf = 0; mf < 4; ++mf)
#pragma unroll
      for (int nf = 0; nf < 4; ++nf)
        acc[mf][nf] = __builtin_amdgcn_mfma_f32_16x16x32_bf16(av[mf], bv[nf], acc[mf][nf], 0, 0, 0);
    __builtin_amdgcn_s_setprio(0);

#pragma unroll
    for (int mf = 0; mf < 4; ++mf) av[mf] = *(const bf16x8*)(As + aoff[mf + 4]);
    if (do_pf) stageB(pbuf, pf * 32);
    __builtin_amdgcn_s_setprio(1);
#pragma unroll
    for (int mf = 0; mf < 4; ++mf)
#pragma unroll
      for (int nf = 0; nf < 4; ++nf)
        acc[mf + 4][nf] = __builtin_amdgcn_mfma_f32_16x16x32_bf16(av[mf], bv[nf], acc[mf + 4][nf], 0, 0, 0);
    __builtin_amdgcn_s_setprio(0);

    __builtin_amdgcn_sched_barrier(0);
    if (tt + 3 < NT)      asm volatile("s_waitcnt vmcnt(8)" ::: "memory");
    else if (tt + 2 < NT) asm volatile("s_waitcnt vmcnt(4)" ::: "memory");
    else if (tt + 1 < NT) asm volatile("s_waitcnt vmcnt(0)" ::: "memory");
    if (tt + 1 < NT) {
      __builtin_amdgcn_s_barrier();
      __builtin_amdgcn_sched_barrier(0);
    }
  }

  if (EPI == 2) {
#pragma unroll
    for (int mf = 0; mf < 8; ++mf) {
#pragma unroll
      for (int nh = 0; nh < 2; ++nh) {
        const int nf = nh * 2;
        const int sc = n0 + nbase + nf * 16;
        const float bg = bias[sc + l15], bt = bias[sc + 16 + l15];
        const float fg = fvec[sc + l15], ft = fvec[sc + 16 + l15];
        const int ocol = (sc >> 5) * 16 + l15;
#pragma unroll
        for (int j = 0; j < 4; ++j) {
          const int row = m0 + mbase + mf * 16 + lg * 4 + j;
          const float flg = flags[row];
          float g  = acc[mf][nf][j]     + bg + flg * fg;
          float tv = acc[mf][nf + 1][j] + bt + flg * ft;
          ((__hip_bfloat16*)C)[(size_t)row * ldc + ocol] =
              __float2bfloat16(sigmoid_f(g) * gelu_f(tv));
        }
      }
    }
    return;
  }
#pragma unroll
  for (int mf = 0; mf < 8; ++mf)
#pragma unroll
    for (int nf = 0; nf < 4; ++nf) {
      const int col = n0 + nbase + nf * 16 + l15;
      const float bc = bias ? bias[col] : 0.f;
#pragma unroll
      for (int j = 0; j < 4; ++j) {
        const int row = m0 + mbase + mf * 16 + lg * 4 + j;
        ((__hip_bfloat16*)C)[(size_t)row * ldc + col] =
            __float2bfloat16(acc[mf][nf][j] + bc);
      }
    }
}

// ---------------------------------------------------------------------------
// 128x128 2-phase GEMM (small/odd shapes: child GEMM, weight folds)
// ---------------------------------------------------------------------------
template<int EPI, bool OBF16>
__global__ __launch_bounds__(256)
void gemm_kernel(const __hip_bfloat16* __restrict__ A0, int lda0,
                 const __hip_bfloat16* __restrict__ A1, int lda1,
                 const __hip_bfloat16* __restrict__ A2, int lda2,
                 int ks1, int ks2,
                 const __hip_bfloat16* __restrict__ B, int ldb,
                 const float* __restrict__ bias,
                 const float* __restrict__ fvec,
                 const float* __restrict__ flags,
                 void* __restrict__ C, int ldc, int K)
{
  __shared__ __align__(16) __hip_bfloat16 As[128 * 32];
  __shared__ __align__(16) __hip_bfloat16 Bs[128 * 32];
  const int t = threadIdx.x;
  const int l = t & 63, w = t >> 6;
  const int gx = gridDim.x;
  int bid = blockIdx.y * gx + blockIdx.x;
  {
    const int nwg = gx * gridDim.y;
    const int xcd = bid & 7, rk = bid >> 3, q = nwg >> 3, r = nwg & 7;
    bid = (xcd < r ? xcd * (q + 1) : r * (q + 1) + (xcd - r) * q) + rk;
  }
  const int m0 = (bid / gx) * 128, n0 = (bid % gx) * 128;
  const int wm = (w >> 1) * 64, wn = (w & 1) * 64;
  const int l15 = l & 15, lg = l >> 4;

  const int r0 = t >> 2;
  const int kk0 = ((t & 3) ^ ((t >> 3) & 3)) * 8;
  char* lA = (char*)As + t * 16;
  char* lB = (char*)Bs + t * 16;
  const size_t boff1 = (size_t)(n0 + r0) * ldb + kk0;
  const size_t boff2 = (size_t)(n0 + r0 + 64) * ldb + kk0;

  int aoffR[4], boffR[4];
#pragma unroll
  for (int i = 0; i < 4; ++i) {
    const int ra = wm + i * 16 + l15;
    aoffR[i] = ra * 32 + ((lg ^ ((ra >> 1) & 3)) * 8);
    const int rb = wn + i * 16 + l15;
    boffR[i] = rb * 32 + ((lg ^ ((rb >> 1) & 3)) * 8);
  }
  f32x4 acc[4][4] = {};

#pragma unroll 1
  for (int seg = 0; seg < 3; ++seg) {
    const __hip_bfloat16* Ap;
    int ldA, kb, ke;
    if (seg == 0)      { Ap = A0; ldA = lda0; kb = 0;   ke = ks1; }
    else if (seg == 1) { Ap = A1; ldA = lda1; kb = ks1; ke = ks2; }
    else               { Ap = A2; ldA = lda2; kb = ks2; ke = K;   }
    if (kb >= ke) continue;
    const size_t aoff1 = (size_t)(m0 + r0) * ldA + kk0;
    const size_t aoff2 = (size_t)(m0 + r0 + 64) * ldA + kk0;
    for (int k0 = kb; k0 < ke; k0 += 32) {
      const int kr = k0 - kb;
      gload16(Ap + aoff1 + kr, lA);
      gload16(Ap + aoff2 + kr, lA + 4096);
      gload16(B + boff1 + k0, lB);
      gload16(B + boff2 + k0, lB + 4096);
      __syncthreads();
      bf16x8 af[4], bfr[4];
#pragma unroll
      for (int i = 0; i < 4; ++i) {
        af[i]  = *(const bf16x8*)((const __hip_bfloat16*)As + aoffR[i]);
        bfr[i] = *(const bf16x8*)((const __hip_bfloat16*)Bs + boffR[i]);
      }
#pragma unroll
      for (int mi = 0; mi < 4; ++mi)
#pragma unroll
        for (int ni = 0; ni < 4; ++ni)
          acc[mi][ni] = __builtin_amdgcn_mfma_f32_16x16x32_bf16(af[mi], bfr[ni], acc[mi][ni], 0, 0, 0);
      __syncthreads();
    }
  }

#pragma unroll
  for (int mi = 0; mi < 4; ++mi)
#pragma unroll
    for (int ni = 0; ni < 4; ++ni) {
      const int col = n0 + wn + ni * 16 + l15;
      const float bc = bias ? bias[col] : 0.f;
#pragma unroll
      for (int j = 0; j < 4; ++j) {
        const int row = m0 + wm + mi * 16 + lg * 4 + j;
        float v = acc[mi][ni][j] + bc;
        if (EPI == 1) v = gelu_f(v);
        if (OBF16) ((__hip_bfloat16*)C)[(size_t)row * ldc + col] = __float2bfloat16(v);
        else       ((float*)C)[(size_t)row * ldc + col] = v;
      }
    }
}

// ---------------------------------------------------------------------------
// Merged attention: blocks 0..1023 = head attn, 1024..2047 = sibling attn.
// ---------------------------------------------------------------------------
__global__ __launch_bounds__(256)
void attn_kernel(const __hip_bfloat16* __restrict__ QKV,
                 const int* __restrict__ pred_heads,
                 const int* __restrict__ mask,
                 __hip_bfloat16* __restrict__ Oout,
                 float* __restrict__ flags)
{
  __shared__ __align__(16) __hip_bfloat16 smem[128 * 128];  // Q|K, later P
  __shared__ __align__(16) __hip_bfloat16 Vt[64 * 128];     // V transposed
  __shared__ int hs[128];
  __shared__ int mk[128];
  const bool SIB = blockIdx.x >= 1024;
  const int bh = blockIdx.x & 1023;
  const int b = bh >> 3, h = bh & 7;
  const int qofs = SIB ? 1536 : 0;
  __hip_bfloat16* Ob = Oout + (SIB ? 512 : 0);
  const int t = threadIdx.x, l = t & 63, w = t >> 6;
  const int l15 = l & 15, lg = l >> 4;
  __hip_bfloat16* Qs = smem;
  __hip_bfloat16* Ks = smem + 128 * 64;

  if (t < 128) {
    int hh = pred_heads[b * 128 + t];
    hh = hh < 0 ? 0 : (hh > 127 ? 127 : hh);
    hs[t] = hh;
    mk[t] = mask[b * 128 + t];
  }
  __syncthreads();
  const size_t tb = (size_t)b * 128 * 3072;
  const int co = qofs + h * 64;
#pragma unroll
  for (int it = 0; it < 4; ++it) {
    const int idx = it * 256 + t;
    const int row = idx >> 3;
    const int c8 = (idx & 7) * 8;
    const int sl = ((c8 >> 3) ^ (row & 7)) * 8;
    *(uint4*)(Qs + row * 64 + sl) = *(const uint4*)(QKV + tb + (size_t)row * 3072 + co + c8);
    const int krow = SIB ? row : hs[row];
    *(uint4*)(Ks + row * 64 + sl) = *(const uint4*)(QKV + tb + (size_t)krow * 3072 + co + 512 + c8);
    uint4 vv = *(const uint4*)(QKV + tb + (size_t)krow * 3072 + co + 1024 + c8);
    const __hip_bfloat16* vp = (const __hip_bfloat16*)&vv;
#pragma unroll
    for (int u = 0; u < 8; ++u) {
      const int d = c8 + u;
      Vt[d * 128 + (((row >> 3) ^ (d & 7)) * 8) + (row & 7)] = vp[u];
    }
  }
  __syncthreads();

  const int r0 = w * 32;
  f32x4 s[2][8] = {};
  const int x7 = l15 & 7;
#pragma unroll
  for (int ks = 0; ks < 2; ++ks) {
    const int sl = ((ks * 4 + lg) ^ x7) * 8;
    bf16x8 qa0 = *(const bf16x8*)(Qs + (r0 + l15) * 64 + sl);
    bf16x8 qa1 = *(const bf16x8*)(Qs + (r0 + 16 + l15) * 64 + sl);
#pragma unroll
    for (int nj = 0; nj < 8; ++nj) {
      bf16x8 kb = *(const bf16x8*)(Ks + (nj * 16 + l15) * 64 + sl);
      s[0][nj] = __builtin_amdgcn_mfma_f32_16x16x32_bf16(qa0, kb, s[0][nj], 0, 0, 0);
      s[1][nj] = __builtin_amdgcn_mfma_f32_16x16x32_bf16(qa1, kb, s[1][nj], 0, 0, 0);
    }
  }
  const float scale = 0.125f;   // 1/sqrt(64)
  float inv_sum[2][4];
#pragma unroll
  for (int mi = 0; mi < 2; ++mi) {
#pragma unroll
    for (int j = 0; j < 4; ++j) {
      const int row = r0 + mi * 16 + lg * 4 + j;
      float mx = -1e30f;
#pragma unroll
      for (int nj = 0; nj < 8; ++nj) {
        float v = s[mi][nj][j] * scale;
        bool ok = true;
        if (SIB) {
          int c = nj * 16 + l15;
          ok = (hs[row] == hs[c]) && (row != c) && mk[row] && mk[c];
        }
        mx = fmaxf(mx, ok ? v : -1e30f);
      }
#pragma unroll
      for (int m = 1; m < 16; m <<= 1) mx = fmaxf(mx, __shfl_xor(mx, m));
      float sum = 0.f;
#pragma unroll
      for (int nj = 0; nj < 8; ++nj) {
        float v = s[mi][nj][j] * scale;
        bool ok = true;
        if (SIB) {
          int c = nj * 16 + l15;
          ok = (hs[row] == hs[c]) && (row != c) && mk[row] && mk[c];
        }
        float p = ok ? __expf(v - mx) : 0.f;
        s[mi][nj][j] = p;
        sum += p;
      }
#pragma unroll
      for (int m = 1; m < 16; m <<= 1) sum += __shfl_xor(sum, m);
      inv_sum[mi][j] = sum > 0.f ? 1.f / sum : 0.f;
    }
  }
  __syncthreads();
#pragma unroll
  for (int mi = 0; mi < 2; ++mi)
#pragma unroll
    for (int nj = 0; nj < 8; ++nj)
#pragma unroll
      for (int j = 0; j < 4; ++j) {
        const int rr = r0 + mi * 16 + lg * 4 + j;
        const int cc = nj * 16 + l15;
        smem[rr * 128 + (((cc >> 3) ^ (rr & 7)) * 8) + (cc & 7)] = __float2bfloat16(s[mi][nj][j]);
      }
  __syncthreads();

  f32x4 o[2][4] = {};
#pragma unroll
  for (int js = 0; js < 4; ++js) {
    const int slot = js * 4 + lg;
    const int slp = (slot ^ x7) * 8;
    bf16x8 pa0 = *(const bf16x8*)(smem + (r0 + l15) * 128 + slp);
    bf16x8 pa1 = *(const bf16x8*)(smem + (r0 + 16 + l15) * 128 + slp);
#pragma unroll
    for (int dj = 0; dj < 4; ++dj) {
      bf16x8 vb = *(const bf16x8*)(Vt + (dj * 16 + l15) * 128 + slp);
      o[0][dj] = __builtin_amdgcn_mfma_f32_16x16x32_bf16(pa0, vb, o[0][dj], 0, 0, 0);
      o[1][dj] = __builtin_amdgcn_mfma_f32_16x16x32_bf16(pa1, vb, o[1][dj], 0, 0, 0);
    }
  }
  const int hb = h * 64;
#pragma unroll
  for (int mi = 0; mi < 2; ++mi)
#pragma unroll
    for (int dj = 0; dj < 4; ++dj)
#pragma unroll
      for (int j = 0; j < 4; ++j) {
        const int row = r0 + mi * 16 + lg * 4 + j;
        const int dc = dj * 16 + l15;
        const float val = o[mi][dj][j] * inv_sum[mi][j];
        Ob[(size_t)(b * 128 + row) * 1024 + hb + dc] = __float2bfloat16(val);
      }
  if (SIB && h == 0 && l15 == 0) {
#pragma unroll
    for (int mi = 0; mi < 2; ++mi)
#pragma unroll
      for (int j = 0; j < 4; ++j) {
        const int row = r0 + mi * 16 + lg * 4 + j;
        flags[b * 128 + row] = inv_sum[mi][j] > 0.f ? 1.f : 0.f;
      }
  }
}

// ---------------------------------------------------------------------------
// Child aggregation (bf16 input) -> Cavg (bf16, ld 512)
// ---------------------------------------------------------------------------
__global__ __launch_bounds__(256)
void child_kernel(const __hip_bfloat16* __restrict__ Hbf,
                  const int* __restrict__ pred_heads,
                  const int* __restrict__ mask,
                  __hip_bfloat16* __restrict__ Cavg)
{
  __shared__ float sum[128 * 64];
  __shared__ int cnt[128];
  __shared__ int hsl[128];
  __shared__ int vld[128];
  const int t = threadIdx.x;
  const int b = blockIdx.y, ch = blockIdx.x;  // ch in 0..7
#pragma unroll
  for (int u = 0; u < 32; ++u) sum[u * 256 + t] = 0.f;
  if (t < 128) {
    int hh = pred_heads[b * 128 + t];
    hh = hh < 0 ? 0 : (hh > 127 ? 127 : hh);
    hsl[t] = hh;
    vld[t] = (mask[b * 128 + t] != 0) && (t >= 1);
    cnt[t] = 0;
  }
  __syncthreads();
  if (t < 128 && vld[t]) atomicAdd(&cnt[hsl[t]], 1);
  __syncthreads();
  const int c = t & 63;
  const int isub = t >> 6;
  for (int ii = 0; ii < 32; ++ii) {
    int i = ii * 4 + isub;
    if (vld[i])
      atomicAdd(&sum[hsl[i] * 64 + c],
                __bfloat162float(Hbf[((size_t)b * 128 + i) * 512 + ch * 64 + c]));
  }
  __syncthreads();
#pragma unroll
  for (int u = 0; u < 32; ++u) {
    int idx = u * 256 + t;
    int p = idx >> 6, cc = idx & 63;
    float avg = sum[idx] / fmaxf((float)cnt[p], 1.f);
    Cavg[((size_t)b * 128 + p) * 512 + ch * 64 + cc] = __float2bfloat16(avg);
  }
}

// ---------------------------------------------------------------------------
// Merged prep: fp32->bf16 conversions + gate/trans interleave + out-proj T.
// ---------------------------------------------------------------------------
__global__ void prep_kernel(const float* __restrict__ hin_w, const float* __restrict__ sin_w,
                            const float* __restrict__ ch_w, const float* __restrict__ H,
                            __hip_bfloat16* __restrict__ Wqkv, __hip_bfloat16* __restrict__ Wch,
                            __hip_bfloat16* __restrict__ Hbf,
                            const float* __restrict__ gw, const float* __restrict__ tw,
                            const float* __restrict__ gb, const float* __restrict__ tb,
                            __hip_bfloat16* __restrict__ Wf, __hip_bfloat16* __restrict__ Whin,
                            __hip_bfloat16* __restrict__ Wsin, float* __restrict__ bias,
                            const float* __restrict__ hout_w, const float* __restrict__ sout_w,
                            __hip_bfloat16* __restrict__ WhoT, __hip_bfloat16* __restrict__ WsoT)
{
  int gid = blockIdx.x * 256 + threadIdx.x;
  if (gid < 2621440) {
    // 4-wide fp32->bf16 segments
    const float* s; __hip_bfloat16* d; int i;
    if      (gid <  196608) { s = hin_w; d = Wqkv;          i = gid; }
    else if (gid <  393216) { s = sin_w; d = Wqkv + 786432; i = gid - 196608; }
    else if (gid <  524288) { s = ch_w;  d = Wch;           i = gid - 393216; }
    else                    { s = H;     d = Hbf;           i = gid - 524288; }
    i *= 4;
    float4 v = *(const float4*)(s + i);
    union { __hip_bfloat16 h[4]; uint2 u; } p;
    p.h[0] = __float2bfloat16(v.x); p.h[1] = __float2bfloat16(v.y);
    p.h[2] = __float2bfloat16(v.z); p.h[3] = __float2bfloat16(v.w);
    *(uint2*)(d + i) = p.u;
  } else if (gid < 4718592) {
    int idx = gid - 2621440;            // 0..2097151
    int s = idx >> 11, c = idx & 2047;
    int q = s >> 5, r = s & 31;
    float v = (r < 16) ? gw[(size_t)(q * 16 + r) * 2048 + c]
                       : tw[(size_t)(q * 16 + r - 16) * 2048 + c];
    __hip_bfloat16 hv = __float2bfloat16(v);
    if      (c <  512) Wf[(size_t)s * 2048 + c] = hv;
    else if (c < 1024) Whin[(size_t)s * 512 + (c - 512)] = hv;
    else if (c < 1536) Wf[(size_t)s * 2048 + (c - 512)] = hv;
    else               Wsin[(size_t)s * 512 + (c - 1536)] = hv;
    if (c == 0) bias[s] = (r < 16) ? gb[q * 16 + r] : tb[q * 16 + r - 16];
  } else {
    int idx = gid - 4718592;            // 0..524287
    const float* s = hout_w; __hip_bfloat16* d = WhoT;
    if (idx >= 262144) { s = sout_w; d = WsoT; idx -= 262144; }
    int i = idx >> 9, j = idx & 511;
    d[i * 512 + j] = __float2bfloat16(s[(size_t)j * 512 + i]);
  }
}

// bias folds: bias_gt[s] += Whin[s,:].hout_b ; fvec[s] = Wsin[s,:].sout_b
__global__ __launch_bounds__(256)
void foldbias_kernel(const __hip_bfloat16* __restrict__ Whin, const __hip_bfloat16* __restrict__ Wsin,
                     const float* __restrict__ hob, const float* __restrict__ sob,
                     float* __restrict__ bias_gt, float* __restrict__ fvec)
{
  const int s = blockIdx.x * 256 + threadIdx.x;  // 0..1023
  float a = 0.f, c = 0.f;
  for (int j = 0; j < 512; j += 8) {
    bf16x8 wh = *(const bf16x8*)(Whin + (size_t)s * 512 + j);
    bf16x8 wsv = *(const bf16x8*)(Wsin + (size_t)s * 512 + j);
#pragma unroll
    for (int u = 0; u < 8; ++u) {
      a += (float)wh[u] * hob[j + u];
      c += (float)wsv[u] * sob[j + u];
    }
  }
  bias_gt[s] += a;
  fvec[s] = c;
}

__global__ __launch_bounds__(64)
void ln_kernel(const float* __restrict__ H, const __hip_bfloat16* __restrict__ U,
               const float* __restrict__ g, const float* __restrict__ bta,
               float* __restrict__ out)
{
  const int row = blockIdx.x, l = threadIdx.x;
  const size_t hb = (size_t)row * 512;
  const int c0 = l * 8;
  float4 h0 = *(const float4*)(H + hb + c0);
  float4 h1 = *(const float4*)(H + hb + c0 + 4);
  bf16x8 uv = *(const bf16x8*)(U + hb + c0);
  float x[8];
  x[0] = h0.x + (float)uv[0]; x[1] = h0.y + (float)uv[1];
  x[2] = h0.z + (float)uv[2]; x[3] = h0.w + (float)uv[3];
  x[4] = h1.x + (float)uv[4]; x[5] = h1.y + (float)uv[5];
  x[6] = h1.z + (float)uv[6]; x[7] = h1.w + (float)uv[7];
  float sum = 0.f;
#pragma unroll
  for (int u = 0; u < 8; ++u) sum += x[u];
#pragma unroll
  for (int m = 32; m; m >>= 1) sum += __shfl_xor(sum, m);
  const float mean = sum * (1.f / 512.f);
  float vs = 0.f;
#pragma unroll
  for (int u = 0; u < 8; ++u) { float d0 = x[u] - mean; vs += d0 * d0; }
#pragma unroll
  for (int m = 32; m; m >>= 1) vs += __shfl_xor(vs, m);
  const float rstd = rsqrtf(vs * (1.f / 512.f) + 1e-5f);
  float4 g0 = *(const float4*)(g + c0);
  float4 g1 = *(const float4*)(g + c0 + 4);
  float4 b0 = *(const float4*)(bta + c0);
  float4 b1 = *(const float4*)(bta + c0 + 4);
  float4 o0, o1;
  o0.x = (x[0] - mean) * rstd * g0.x + b0.x;
  o0.y = (x[1] - mean) * rstd * g0.y + b0.y;
  o0.z = (x[2] - mean) * rstd * g0.z + b0.z;
  o0.w = (x[3] - mean) * rstd * g0.w + b0.w;
  o1.x = (x[4] - mean) * rstd * g1.x + b1.x;
  o1.y = (x[5] - mean) * rstd * g1.y + b1.y;
  o1.z = (x[6] - mean) * rstd * g1.z + b1.z;
  o1.w = (x[7] - mean) * rstd * g1.w + b1.w;
  *(float4*)(out + hb + c0) = o0;
  *(float4*)(out + hb + c0 + 4) = o1;
}

extern "C" void kernel_launch(void* const* d_in, const int* in_sizes, int n_in,
                              void* d_out, int out_size, void* d_ws, size_t ws_size,
                              hipStream_t stream)
{
  (void)in_sizes; (void)n_in; (void)out_size; (void)ws_size;
  const float* H      = (const float*)d_in[0];
  const int*  pred    = (const int*)d_in[1];
  const int*  maskp   = (const int*)d_in[2];
  const float* hin_w  = (const float*)d_in[3];
  const float* hin_b  = (const float*)d_in[4];
  const float* hout_w = (const float*)d_in[5];
  const float* hout_b = (const float*)d_in[6];
  const float* sin_w  = (const float*)d_in[7];
  const float* sin_b  = (const float*)d_in[8];
  const float* sout_w = (const float*)d_in[9];
  const float* sout_b = (const float*)d_in[10];
  const float* ch_w   = (const float*)d_in[11];
  const float* ch_b   = (const float*)d_in[12];
  const float* g_w    = (const float*)d_in[13];
  const float* g_b    = (const float*)d_in[14];
  const float* t_w    = (const float*)d_in[15];
  const float* t_b    = (const float*)d_in[16];
  const float* lng    = (const float*)d_in[17];
  const float* lnb    = (const float*)d_in[18];

  char* ws = (char*)d_ws;
  __hip_bfloat16* Wqkv  = (__hip_bfloat16*)(ws + 0);          // 3072x512
  __hip_bfloat16* Wch   = (__hip_bfloat16*)(ws + 3145728);    // 512x1024
  __hip_bfloat16* Wgt   = (__hip_bfloat16*)(ws + 4194304);    // 1024x2048 (interleaved)
  float* bias_qkv       = (float*)(ws + 8388608);             // 3072
  float* bias_gt        = (float*)(ws + 8400896);             // 1024
  float* fvec           = (float*)(ws + 8404992);             // 1024
  float* flags          = (float*)(ws + 8409088);             // 16384
  __hip_bfloat16* Hbf   = (__hip_bfloat16*)(ws + 8474624);    // 16384x512
  char* QKVr            = ws + 25251840;                      // big region
  __hip_bfloat16* QKV   = (__hip_bfloat16*)QKVr;              // 16384x3072
  __hip_bfloat16* Whin  = (__hip_bfloat16*)(QKVr + 0);        // 1024x512 (pre-QKV)
  __hip_bfloat16* Wsin  = (__hip_bfloat16*)(QKVr + 1048576);  // 1024x512
  __hip_bfloat16* WhoT  = (__hip_bfloat16*)(QKVr + 2097152);  // 512x512
  __hip_bfloat16* WsoT  = (__hip_bfloat16*)(QKVr + 2621440);  // 512x512
  __hip_bfloat16* CHM   = (__hip_bfloat16*)(QKVr + 0);           // 16384x512 (post-attn)
  __hip_bfloat16* U     = (__hip_bfloat16*)(QKVr + 16777216);    // 16384x512 bf16
  __hip_bfloat16* Cavg  = (__hip_bfloat16*)(QKVr + 50331648);    // 16384x512
  __hip_bfloat16* CM2   = (__hip_bfloat16*)(ws + 125915136);  // 16384x1024 [Ohead|Osib]

  hipFuncSetAttribute(reinterpret_cast<const void*>(gemm8_kernel<0>),
                      hipFuncAttributeMaxDynamicSharedMemorySize, 131072);
  hipFuncSetAttribute(reinterpret_cast<const void*>(gemm8_kernel<2>),
                      hipFuncAttributeMaxDynamicSharedMemorySize, 131072);

  // merged prep (conversions + gate/trans interleave + out-proj transpose)
  prep_kernel<<<20480, 256, 0, stream>>>(hin_w, sin_w, ch_w, H, Wqkv, Wch, Hbf,
                                         g_w, t_w, g_b, t_b, Wgt, Whin, Wsin, bias_gt,
                                         hout_w, sout_w, WhoT, WsoT);
  foldbias_kernel<<<4, 256, 0, stream>>>(Whin, Wsin, hout_b, sout_b, bias_gt, fvec);
  hipMemcpyAsync(bias_qkv, hin_b, 1536 * 4, hipMemcpyDeviceToDevice, stream);
  hipMemcpyAsync(bias_qkv + 1536, sin_b, 1536 * 4, hipMemcpyDeviceToDevice, stream);

  // weight folds: Wgt[:,1024:1536] = Whin @ WhoT^T ; Wgt[:,1536:2048] = Wsin @ WsoT^T
  gemm_kernel<0, true><<<dim3(4, 8), 256, 0, stream>>>(
      Whin, 512, Whin, 512, Whin, 512, 512, 512, WhoT, 512,
      (const float*)nullptr, (const float*)nullptr, (const float*)nullptr,
      (void*)(Wgt + 1024), 2048, 512);
  gemm_kernel<0, true><<<dim3(4, 8), 256, 0, stream>>>(
      Wsin, 512, Wsin, 512, Wsin, 512, 512, 512, WsoT, 512,
      (const float*)nullptr, (const float*)nullptr, (const float*)nullptr,
      (void*)(Wgt + 1536), 2048, 512);

  // fused QKV projection (8-wave 256x256 pipelined)
  gemm8_kernel<0><<<dim3(12, 64), 512, 131072, stream>>>(
      Hbf, 512, Hbf, 512, Hbf, 512, 512, 512, Wqkv, 512,
      bias_qkv, (const float*)nullptr, (const float*)nullptr,
      (void*)QKV, 3072, 512);

  // merged attention (head + sib) -> CM2 slices
  attn_kernel<<<2048, 256, 0, stream>>>(QKV, pred, maskp, CM2, flags);

  // child aggregation (bf16 input) + child message GEMM (QKV dead now)
  child_kernel<<<dim3(8, 128), 256, 0, stream>>>(Hbf, pred, maskp, Cavg);
  gemm_kernel<1, true><<<dim3(4, 128), 256, 0, stream>>>(
      Hbf, 512, Cavg, 512, Cavg, 512, 512, 1024, Wch, 1024,
      ch_b, (const float*)nullptr, (const float*)nullptr,
      (void*)CHM, 512, 1024);

  // fused gate/trans GEMM (8-wave pipelined) over virtual comb = [Hbf | CHM | CM2]
  gemm8_kernel<2><<<dim3(4, 64), 512, 131072, stream>>>(
      Hbf, 512, CHM, 512, CM2, 1024, 512, 1024, Wgt, 2048,
      bias_gt, fvec, flags, (void*)U, 512, 2048);

  // residual + layernorm -> d_out
  ln_kernel<<<16384, 64, 0, stream>>>(H, U, lng, lnb, (float*)d_out);
}

// Round 8
// 453.875 us; speedup vs baseline: 1.1215x; 1.1215x over previous
//
#include <hip/hip_runtime.h>
#include <hip/hip_bf16.h>

typedef __bf16 bf16x8 __attribute__((ext_vector_type(8)));
typedef float f32x4 __attribute__((ext_vector_type(4)));

__device__ __forceinline__ void gload16(const void* g, void* l) {
  __builtin_amdgcn_global_load_lds(
      (const __attribute__((address_space(1))) unsigned int*)g,
      (__attribute__((address_space(3))) unsigned int*)l, 16, 0, 0);
}

__device__ __forceinline__ float gelu_f(float x) {
  return 0.5f * x * (1.f + erff(x * 0.70710678118654752f));
}
__device__ __forceinline__ float sigmoid_f(float x) {
  return 1.f / (1.f + __expf(-x));
}

// ---------------------------------------------------------------------------
// 8-wave 256x256 deep-pipelined GEMM (T3+T4+T5): BK=32, 4 LDS buffers
// (128 KiB dynamic), prefetch depth 3, counted vmcnt(8) (never 0 in loop).
// EPI: 0 = bias+bf16, 2 = gate fusion -> bf16 U.
// ---------------------------------------------------------------------------
template<int EPI>
__global__ __launch_bounds__(512, 2)
void gemm8_kernel(const __hip_bfloat16* __restrict__ A0, int lda0,
                  const __hip_bfloat16* __restrict__ A1, int lda1,
                  const __hip_bfloat16* __restrict__ A2, int lda2,
                  int ks1, int ks2,
                  const __hip_bfloat16* __restrict__ B, int ldb,
                  const float* __restrict__ bias,
                  const float* __restrict__ fvec,
                  const float* __restrict__ flags,
                  void* __restrict__ C, int ldc, int K)
{
  extern __shared__ __align__(16) char lds[];
  const int t = threadIdx.x;
  const int l = t & 63;
  const int w = t >> 6;
  const int l15 = l & 15, lg = (l >> 4) & 3;
  const int orig = blockIdx.y * gridDim.x + blockIdx.x;
  const int nwg = gridDim.x * gridDim.y;
  const int gy = gridDim.y;
  const int xcd = orig & 7, rk = orig >> 3, q = nwg >> 3, r = nwg & 7;
  const int bid = (xcd < r ? xcd * (q + 1) : r * (q + 1) + (xcd - r) * q) + rk;
  const int m0 = (bid % gy) * 256;
  const int n0 = (bid / gy) * 256;

  const int srow = t >> 2;
  const int kc8 = ((t & 3) ^ ((t >> 3) & 3)) * 8;
  const int mbase = (w >> 2) * 128;
  const int nbase = (w & 3) * 64;
  const int swz = (l15 >> 1) & 3;
  const int kslot = (lg ^ swz) * 8;
  int aoff[8], boff[4];
#pragma unroll
  for (int mf = 0; mf < 8; ++mf) aoff[mf] = (mbase + mf * 16 + l15) * 32 + kslot;
#pragma unroll
  for (int nf = 0; nf < 4; ++nf) boff[nf] = (nbase + nf * 16 + l15) * 32 + kslot;

  auto segA = [&](int k0, const __hip_bfloat16*& Ap, int& ldA, int& krel) {
    if (k0 >= ks2)      { Ap = A2; ldA = lda2; krel = k0 - ks2; }
    else if (k0 >= ks1) { Ap = A1; ldA = lda1; krel = k0 - ks1; }
    else                { Ap = A0; ldA = lda0; krel = k0; }
  };
  auto stageA = [&](int buf, const __hip_bfloat16* Ap, int ldA, int krel) {
    char* base = lds + buf * 32768 + t * 16;
    gload16(Ap + (size_t)(m0 + srow) * ldA + krel + kc8, base);
    gload16(Ap + (size_t)(m0 + 128 + srow) * ldA + krel + kc8, base + 8192);
  };
  auto stageB = [&](int buf, int k0) {
    char* base = lds + buf * 32768 + 16384 + t * 16;
    gload16(B + (size_t)(n0 + srow) * ldb + k0 + kc8, base);
    gload16(B + (size_t)(n0 + 128 + srow) * ldb + k0 + kc8, base + 8192);
  };

  f32x4 acc[8][4] = {};
  const int NT = K >> 5;

#pragma unroll 1
  for (int pt = 0; pt < 3; ++pt) {
    const __hip_bfloat16* Ap; int ldA, krel;
    segA(pt * 32, Ap, ldA, krel);
    stageA(pt, Ap, ldA, krel);
    stageB(pt, pt * 32);
  }
  asm volatile("s_waitcnt vmcnt(8)" ::: "memory");
  __builtin_amdgcn_s_barrier();
  __builtin_amdgcn_sched_barrier(0);

#pragma unroll 1
  for (int tt = 0; tt < NT; ++tt) {
    const int buf = tt & 3;
    const __hip_bfloat16* As = (const __hip_bfloat16*)(lds + buf * 32768);
    const __hip_bfloat16* Bs = (const __hip_bfloat16*)(lds + buf * 32768 + 16384);
    const int pf = tt + 3;
    const bool do_pf = pf < NT;
    const int pbuf = pf & 3;
    const __hip_bfloat16* Ap = A0; int ldA = lda0, krel = 0;
    if (do_pf) segA(pf * 32, Ap, ldA, krel);

    bf16x8 bv[4], av[4];
#pragma unroll
    for (int nf = 0; nf < 4; ++nf) bv[nf] = *(const bf16x8*)(Bs + boff[nf]);
#pragma unroll
    for (int mf = 0; mf < 4; ++mf) av[mf] = *(const bf16x8*)(As + aoff[mf]);
    if (do_pf) stageA(pbuf, Ap, ldA, krel);
    __builtin_amdgcn_s_setprio(1);
#pragma unroll
    for (int mf = 0; mf < 4; ++mf)
#pragma unroll
      for (int nf = 0; nf < 4; ++nf)
        acc[mf][nf] = __builtin_amdgcn_mfma_f32_16x16x32_bf16(av[mf], bv[nf], acc[mf][nf], 0, 0, 0);
    __builtin_amdgcn_s_setprio(0);

#pragma unroll
    for (int mf = 0; mf < 4; ++mf) av[mf] = *(const bf16x8*)(As + aoff[mf + 4]);
    if (do_pf) stageB(pbuf, pf * 32);
    __builtin_amdgcn_s_setprio(1);
#pragma unroll
    for (int mf = 0; mf < 4; ++mf)
#pragma unroll
      for (int nf = 0; nf < 4; ++nf)
        acc[mf + 4][nf] = __builtin_amdgcn_mfma_f32_16x16x32_bf16(av[mf], bv[nf], acc[mf + 4][nf], 0, 0, 0);
    __builtin_amdgcn_s_setprio(0);

    __builtin_amdgcn_sched_barrier(0);
    if (tt + 3 < NT)      asm volatile("s_waitcnt vmcnt(8)" ::: "memory");
    else if (tt + 2 < NT) asm volatile("s_waitcnt vmcnt(4)" ::: "memory");
    else if (tt + 1 < NT) asm volatile("s_waitcnt vmcnt(0)" ::: "memory");
    if (tt + 1 < NT) {
      __builtin_amdgcn_s_barrier();
      __builtin_amdgcn_sched_barrier(0);
    }
  }

  if (EPI == 2) {
#pragma unroll
    for (int mf = 0; mf < 8; ++mf) {
#pragma unroll
      for (int nh = 0; nh < 2; ++nh) {
        const int nf = nh * 2;
        const int sc = n0 + nbase + nf * 16;
        const float bg = bias[sc + l15], bt = bias[sc + 16 + l15];
        const float fg = fvec[sc + l15], ft = fvec[sc + 16 + l15];
        const int ocol = (sc >> 5) * 16 + l15;
#pragma unroll
        for (int j = 0; j < 4; ++j) {
          const int row = m0 + mbase + mf * 16 + lg * 4 + j;
          const float flg = flags[row];
          float g  = acc[mf][nf][j]     + bg + flg * fg;
          float tv = acc[mf][nf + 1][j] + bt + flg * ft;
          ((__hip_bfloat16*)C)[(size_t)row * ldc + ocol] =
              __float2bfloat16(sigmoid_f(g) * gelu_f(tv));
        }
      }
    }
    return;
  }
#pragma unroll
  for (int mf = 0; mf < 8; ++mf)
#pragma unroll
    for (int nf = 0; nf < 4; ++nf) {
      const int col = n0 + nbase + nf * 16 + l15;
      const float bc = bias ? bias[col] : 0.f;
#pragma unroll
      for (int j = 0; j < 4; ++j) {
        const int row = m0 + mbase + mf * 16 + lg * 4 + j;
        ((__hip_bfloat16*)C)[(size_t)row * ldc + col] =
            __float2bfloat16(acc[mf][nf][j] + bc);
      }
    }
}

// ---------------------------------------------------------------------------
// 128x128 2-phase GEMM (small/odd shapes: child GEMM, weight folds)
// ---------------------------------------------------------------------------
template<int EPI, bool OBF16>
__global__ __launch_bounds__(256)
void gemm_kernel(const __hip_bfloat16* __restrict__ A0, int lda0,
                 const __hip_bfloat16* __restrict__ A1, int lda1,
                 const __hip_bfloat16* __restrict__ A2, int lda2,
                 int ks1, int ks2,
                 const __hip_bfloat16* __restrict__ B, int ldb,
                 const float* __restrict__ bias,
                 const float* __restrict__ fvec,
                 const float* __restrict__ flags,
                 void* __restrict__ C, int ldc, int K)
{
  __shared__ __align__(16) __hip_bfloat16 As[128 * 32];
  __shared__ __align__(16) __hip_bfloat16 Bs[128 * 32];
  const int t = threadIdx.x;
  const int l = t & 63, w = t >> 6;
  const int gx = gridDim.x;
  int bid = blockIdx.y * gx + blockIdx.x;
  {
    const int nwg = gx * gridDim.y;
    const int xcd = bid & 7, rk = bid >> 3, q = nwg >> 3, r = nwg & 7;
    bid = (xcd < r ? xcd * (q + 1) : r * (q + 1) + (xcd - r) * q) + rk;
  }
  const int m0 = (bid / gx) * 128, n0 = (bid % gx) * 128;
  const int wm = (w >> 1) * 64, wn = (w & 1) * 64;
  const int l15 = l & 15, lg = l >> 4;

  const int r0 = t >> 2;
  const int kk0 = ((t & 3) ^ ((t >> 3) & 3)) * 8;
  char* lA = (char*)As + t * 16;
  char* lB = (char*)Bs + t * 16;
  const size_t boff1 = (size_t)(n0 + r0) * ldb + kk0;
  const size_t boff2 = (size_t)(n0 + r0 + 64) * ldb + kk0;

  int aoffR[4], boffR[4];
#pragma unroll
  for (int i = 0; i < 4; ++i) {
    const int ra = wm + i * 16 + l15;
    aoffR[i] = ra * 32 + ((lg ^ ((ra >> 1) & 3)) * 8);
    const int rb = wn + i * 16 + l15;
    boffR[i] = rb * 32 + ((lg ^ ((rb >> 1) & 3)) * 8);
  }
  f32x4 acc[4][4] = {};

#pragma unroll 1
  for (int seg = 0; seg < 3; ++seg) {
    const __hip_bfloat16* Ap;
    int ldA, kb, ke;
    if (seg == 0)      { Ap = A0; ldA = lda0; kb = 0;   ke = ks1; }
    else if (seg == 1) { Ap = A1; ldA = lda1; kb = ks1; ke = ks2; }
    else               { Ap = A2; ldA = lda2; kb = ks2; ke = K;   }
    if (kb >= ke) continue;
    const size_t aoff1 = (size_t)(m0 + r0) * ldA + kk0;
    const size_t aoff2 = (size_t)(m0 + r0 + 64) * ldA + kk0;
    for (int k0 = kb; k0 < ke; k0 += 32) {
      const int kr = k0 - kb;
      gload16(Ap + aoff1 + kr, lA);
      gload16(Ap + aoff2 + kr, lA + 4096);
      gload16(B + boff1 + k0, lB);
      gload16(B + boff2 + k0, lB + 4096);
      __syncthreads();
      bf16x8 af[4], bfr[4];
#pragma unroll
      for (int i = 0; i < 4; ++i) {
        af[i]  = *(const bf16x8*)((const __hip_bfloat16*)As + aoffR[i]);
        bfr[i] = *(const bf16x8*)((const __hip_bfloat16*)Bs + boffR[i]);
      }
#pragma unroll
      for (int mi = 0; mi < 4; ++mi)
#pragma unroll
        for (int ni = 0; ni < 4; ++ni)
          acc[mi][ni] = __builtin_amdgcn_mfma_f32_16x16x32_bf16(af[mi], bfr[ni], acc[mi][ni], 0, 0, 0);
      __syncthreads();
    }
  }

#pragma unroll
  for (int mi = 0; mi < 4; ++mi)
#pragma unroll
    for (int ni = 0; ni < 4; ++ni) {
      const int col = n0 + wn + ni * 16 + l15;
      const float bc = bias ? bias[col] : 0.f;
#pragma unroll
      for (int j = 0; j < 4; ++j) {
        const int row = m0 + wm + mi * 16 + lg * 4 + j;
        float v = acc[mi][ni][j] + bc;
        if (EPI == 1) v = gelu_f(v);
        if (OBF16) ((__hip_bfloat16*)C)[(size_t)row * ldc + col] = __float2bfloat16(v);
        else       ((float*)C)[(size_t)row * ldc + col] = v;
      }
    }
}

// ---------------------------------------------------------------------------
// Merged attention, swapped-QK^T form: blocks 0..1023 = head, 1024..2047 = sib.
// S^T = mfma(K,Q): lane's C-frag holds 4 contiguous k per q -> in-register
// softmax (2 shfl_xor), normalized-P packed b64 writes (XOR-swizzled).
// ---------------------------------------------------------------------------
__global__ __launch_bounds__(256)
void attn_kernel(const __hip_bfloat16* __restrict__ QKV,
                 const int* __restrict__ pred_heads,
                 const int* __restrict__ mask,
                 __hip_bfloat16* __restrict__ Oout,
                 float* __restrict__ flags)
{
  __shared__ __align__(16) __hip_bfloat16 smem[128 * 128];  // Q|K, later P
  __shared__ __align__(16) __hip_bfloat16 Vt[64 * 128];     // V transposed
  __shared__ int hs[128];
  __shared__ int key[128];
  const bool SIB = blockIdx.x >= 1024;
  const int bh = blockIdx.x & 1023;
  const int b = bh >> 3, h = bh & 7;
  const int qofs = SIB ? 1536 : 0;
  __hip_bfloat16* Ob = Oout + (SIB ? 512 : 0);
  const int t = threadIdx.x, l = t & 63, w = t >> 6;
  const int l15 = l & 15, lg = l >> 4;
  __hip_bfloat16* Qs = smem;
  __hip_bfloat16* Ks = smem + 128 * 64;

  if (t < 128) {
    int hh = pred_heads[b * 128 + t];
    hh = hh < 0 ? 0 : (hh > 127 ? 127 : hh);
    hs[t] = hh;
    key[t] = mask[b * 128 + t] ? hh : (128 + t);
  }
  __syncthreads();
  const size_t tb = (size_t)b * 128 * 3072;
  const int co = qofs + h * 64;
#pragma unroll
  for (int it = 0; it < 4; ++it) {
    const int idx = it * 256 + t;
    const int row = idx >> 3;
    const int c8 = (idx & 7) * 8;
    const int sl = ((c8 >> 3) ^ (row & 7)) * 8;
    *(uint4*)(Qs + row * 64 + sl) = *(const uint4*)(QKV + tb + (size_t)row * 3072 + co + c8);
    const int krow = SIB ? row : hs[row];
    *(uint4*)(Ks + row * 64 + sl) = *(const uint4*)(QKV + tb + (size_t)krow * 3072 + co + 512 + c8);
    uint4 vv = *(const uint4*)(QKV + tb + (size_t)krow * 3072 + co + 1024 + c8);
    const __hip_bfloat16* vp = (const __hip_bfloat16*)&vv;
#pragma unroll
    for (int u = 0; u < 8; ++u) {
      const int d = c8 + u;
      Vt[d * 128 + (((row >> 3) ^ (d & 7)) * 8) + (row & 7)] = vp[u];
    }
  }
  __syncthreads();

  const int r0 = w * 32;
  const int x7 = l15 & 7;
  // QK^T swapped: s[kf][qf] = S^T fragment, m = k (8 tiles), n = q (2 tiles)
  f32x4 s[8][2] = {};
#pragma unroll
  for (int ks = 0; ks < 2; ++ks) {
    const int sl = ((ks * 4 + lg) ^ x7) * 8;
    bf16x8 qb0 = *(const bf16x8*)(Qs + (r0 + l15) * 64 + sl);
    bf16x8 qb1 = *(const bf16x8*)(Qs + (r0 + 16 + l15) * 64 + sl);
#pragma unroll
    for (int kf = 0; kf < 8; ++kf) {
      bf16x8 ka = *(const bf16x8*)(Ks + (kf * 16 + l15) * 64 + sl);
      s[kf][0] = __builtin_amdgcn_mfma_f32_16x16x32_bf16(ka, qb0, s[kf][0], 0, 0, 0);
      s[kf][1] = __builtin_amdgcn_mfma_f32_16x16x32_bf16(ka, qb1, s[kf][1], 0, 0, 0);
    }
  }

  const float scale = 0.125f;   // 1/sqrt(64)
  int kq[2] = {0, 0};
  int4 kv[8];
  if (SIB) {
    kq[0] = key[r0 + l15];
    kq[1] = key[r0 + 16 + l15];
#pragma unroll
    for (int kf = 0; kf < 8; ++kf) kv[kf] = *(const int4*)&key[kf * 16 + lg * 4];
  }
  float invs[2];
#pragma unroll
  for (int qf = 0; qf < 2; ++qf) {
    const int q = r0 + qf * 16 + l15;
    unsigned om = 0xFFFFFFFFu;
    if (SIB) {
      om = 0u;
#pragma unroll
      for (int kf = 0; kf < 8; ++kf) {
        const int* kp = (const int*)&kv[kf];
#pragma unroll
        for (int j = 0; j < 4; ++j) {
          const int k = kf * 16 + lg * 4 + j;
          if (kp[j] == kq[qf] && k != q) om |= (1u << (kf * 4 + j));
        }
      }
    }
    float mx = -1e30f;
#pragma unroll
    for (int kf = 0; kf < 8; ++kf)
#pragma unroll
      for (int j = 0; j < 4; ++j) {
        const float v = s[kf][qf][j] * scale;
        mx = fmaxf(mx, ((om >> (kf * 4 + j)) & 1u) ? v : -1e30f);
      }
    mx = fmaxf(mx, __shfl_xor(mx, 16));
    mx = fmaxf(mx, __shfl_xor(mx, 32));
    float sum = 0.f;
#pragma unroll
    for (int kf = 0; kf < 8; ++kf)
#pragma unroll
      for (int j = 0; j < 4; ++j) {
        const float v = s[kf][qf][j] * scale;
        const float p = ((om >> (kf * 4 + j)) & 1u) ? __expf(v - mx) : 0.f;
        s[kf][qf][j] = p;
        sum += p;
      }
    sum += __shfl_xor(sum, 16);
    sum += __shfl_xor(sum, 32);
    invs[qf] = sum > 0.f ? 1.f / sum : 0.f;
  }
  if (SIB && h == 0 && lg == 0) {
    flags[b * 128 + r0 + l15]      = invs[0] > 0.f ? 1.f : 0.f;
    flags[b * 128 + r0 + 16 + l15] = invs[1] > 0.f ? 1.f : 0.f;
  }

  __syncthreads();  // all waves done reading Qs/Ks
  // normalized P -> smem[q][k], packed b64, chunk swizzle c16' = c16 ^ (q&7)
#pragma unroll
  for (int qf = 0; qf < 2; ++qf) {
    const int q = r0 + qf * 16 + l15;
    const int base = q * 128 + ((lg & 1) << 2);
#pragma unroll
    for (int kf = 0; kf < 8; ++kf) {
      const int c16 = kf * 2 + (lg >> 1);
      __hip_bfloat16 pk[4];
#pragma unroll
      for (int j = 0; j < 4; ++j) pk[j] = __float2bfloat16(s[kf][qf][j] * invs[qf]);
      *(uint2*)(smem + base + ((c16 ^ x7) << 3)) = *(const uint2*)pk;
    }
  }
  __syncthreads();

  f32x4 o[2][4] = {};
#pragma unroll
  for (int js = 0; js < 4; ++js) {
    const int slp = ((js * 4 + lg) ^ x7) * 8;
    bf16x8 pa0 = *(const bf16x8*)(smem + (r0 + l15) * 128 + slp);
    bf16x8 pa1 = *(const bf16x8*)(smem + (r0 + 16 + l15) * 128 + slp);
#pragma unroll
    for (int dj = 0; dj < 4; ++dj) {
      bf16x8 vb = *(const bf16x8*)(Vt + (dj * 16 + l15) * 128 + slp);
      o[0][dj] = __builtin_amdgcn_mfma_f32_16x16x32_bf16(pa0, vb, o[0][dj], 0, 0, 0);
      o[1][dj] = __builtin_amdgcn_mfma_f32_16x16x32_bf16(pa1, vb, o[1][dj], 0, 0, 0);
    }
  }
  const int hb = h * 64;
#pragma unroll
  for (int mi = 0; mi < 2; ++mi)
#pragma unroll
    for (int dj = 0; dj < 4; ++dj)
#pragma unroll
      for (int j = 0; j < 4; ++j) {
        const int row = r0 + mi * 16 + lg * 4 + j;
        const int dc = dj * 16 + l15;
        Ob[(size_t)(b * 128 + row) * 1024 + hb + dc] = __float2bfloat16(o[mi][dj][j]);
      }
}

// ---------------------------------------------------------------------------
// Child aggregation (bf16 input) -> Cavg (bf16, ld 512)
// ---------------------------------------------------------------------------
__global__ __launch_bounds__(256)
void child_kernel(const __hip_bfloat16* __restrict__ Hbf,
                  const int* __restrict__ pred_heads,
                  const int* __restrict__ mask,
                  __hip_bfloat16* __restrict__ Cavg)
{
  __shared__ float sum[128 * 64];
  __shared__ int cnt[128];
  __shared__ int hsl[128];
  __shared__ int vld[128];
  const int t = threadIdx.x;
  const int b = blockIdx.y, ch = blockIdx.x;  // ch in 0..7
#pragma unroll
  for (int u = 0; u < 32; ++u) sum[u * 256 + t] = 0.f;
  if (t < 128) {
    int hh = pred_heads[b * 128 + t];
    hh = hh < 0 ? 0 : (hh > 127 ? 127 : hh);
    hsl[t] = hh;
    vld[t] = (mask[b * 128 + t] != 0) && (t >= 1);
    cnt[t] = 0;
  }
  __syncthreads();
  if (t < 128 && vld[t]) atomicAdd(&cnt[hsl[t]], 1);
  __syncthreads();
  const int c = t & 63;
  const int isub = t >> 6;
  for (int ii = 0; ii < 32; ++ii) {
    int i = ii * 4 + isub;
    if (vld[i])
      atomicAdd(&sum[hsl[i] * 64 + c],
                __bfloat162float(Hbf[((size_t)b * 128 + i) * 512 + ch * 64 + c]));
  }
  __syncthreads();
#pragma unroll
  for (int u = 0; u < 32; ++u) {
    int idx = u * 256 + t;
    int p = idx >> 6, cc = idx & 63;
    float avg = sum[idx] / fmaxf((float)cnt[p], 1.f);
    Cavg[((size_t)b * 128 + p) * 512 + ch * 64 + cc] = __float2bfloat16(avg);
  }
}

// ---------------------------------------------------------------------------
// Merged prep: fp32->bf16 conversions + gate/trans interleave + out-proj T.
// ---------------------------------------------------------------------------
__global__ void prep_kernel(const float* __restrict__ hin_w, const float* __restrict__ sin_w,
                            const float* __restrict__ ch_w, const float* __restrict__ H,
                            __hip_bfloat16* __restrict__ Wqkv, __hip_bfloat16* __restrict__ Wch,
                            __hip_bfloat16* __restrict__ Hbf,
                            const float* __restrict__ gw, const float* __restrict__ tw,
                            const float* __restrict__ gb, const float* __restrict__ tb,
                            __hip_bfloat16* __restrict__ Wf, __hip_bfloat16* __restrict__ Whin,
                            __hip_bfloat16* __restrict__ Wsin, float* __restrict__ bias,
                            const float* __restrict__ hout_w, const float* __restrict__ sout_w,
                            __hip_bfloat16* __restrict__ WhoT, __hip_bfloat16* __restrict__ WsoT)
{
  int gid = blockIdx.x * 256 + threadIdx.x;
  if (gid < 2621440) {
    const float* s; __hip_bfloat16* d; int i;
    if      (gid <  196608) { s = hin_w; d = Wqkv;          i = gid; }
    else if (gid <  393216) { s = sin_w; d = Wqkv + 786432; i = gid - 196608; }
    else if (gid <  524288) { s = ch_w;  d = Wch;           i = gid - 393216; }
    else                    { s = H;     d = Hbf;           i = gid - 524288; }
    i *= 4;
    float4 v = *(const float4*)(s + i);
    union { __hip_bfloat16 h[4]; uint2 u; } p;
    p.h[0] = __float2bfloat16(v.x); p.h[1] = __float2bfloat16(v.y);
    p.h[2] = __float2bfloat16(v.z); p.h[3] = __float2bfloat16(v.w);
    *(uint2*)(d + i) = p.u;
  } else if (gid < 4718592) {
    int idx = gid - 2621440;            // 0..2097151
    int s = idx >> 11, c = idx & 2047;
    int q = s >> 5, r = s & 31;
    float v = (r < 16) ? gw[(size_t)(q * 16 + r) * 2048 + c]
                       : tw[(size_t)(q * 16 + r - 16) * 2048 + c];
    __hip_bfloat16 hv = __float2bfloat16(v);
    if      (c <  512) Wf[(size_t)s * 2048 + c] = hv;
    else if (c < 1024) Whin[(size_t)s * 512 + (c - 512)] = hv;
    else if (c < 1536) Wf[(size_t)s * 2048 + (c - 512)] = hv;
    else               Wsin[(size_t)s * 512 + (c - 1536)] = hv;
    if (c == 0) bias[s] = (r < 16) ? gb[q * 16 + r] : tb[q * 16 + r - 16];
  } else {
    int idx = gid - 4718592;            // 0..524287
    const float* s = hout_w; __hip_bfloat16* d = WhoT;
    if (idx >= 262144) { s = sout_w; d = WsoT; idx -= 262144; }
    int i = idx >> 9, j = idx & 511;
    d[i * 512 + j] = __float2bfloat16(s[(size_t)j * 512 + i]);
  }
}

// bias folds: bias_gt[s] += Whin[s,:].hout_b ; fvec[s] = Wsin[s,:].sout_b
__global__ __launch_bounds__(256)
void foldbias_kernel(const __hip_bfloat16* __restrict__ Whin, const __hip_bfloat16* __restrict__ Wsin,
                     const float* __restrict__ hob, const float* __restrict__ sob,
                     float* __restrict__ bias_gt, float* __restrict__ fvec)
{
  const int s = blockIdx.x * 256 + threadIdx.x;  // 0..1023
  float a = 0.f, c = 0.f;
  for (int j = 0; j < 512; j += 8) {
    bf16x8 wh = *(const bf16x8*)(Whin + (size_t)s * 512 + j);
    bf16x8 wsv = *(const bf16x8*)(Wsin + (size_t)s * 512 + j);
#pragma unroll
    for (int u = 0; u < 8; ++u) {
      a += (float)wh[u] * hob[j + u];
      c += (float)wsv[u] * sob[j + u];
    }
  }
  bias_gt[s] += a;
  fvec[s] = c;
}

__global__ __launch_bounds__(64)
void ln_kernel(const float* __restrict__ H, const __hip_bfloat16* __restrict__ U,
               const float* __restrict__ g, const float* __restrict__ bta,
               float* __restrict__ out)
{
  const int row = blockIdx.x, l = threadIdx.x;
  const size_t hb = (size_t)row * 512;
  const int c0 = l * 8;
  float4 h0 = *(const float4*)(H + hb + c0);
  float4 h1 = *(const float4*)(H + hb + c0 + 4);
  bf16x8 uv = *(const bf16x8*)(U + hb + c0);
  float x[8];
  x[0] = h0.x + (float)uv[0]; x[1] = h0.y + (float)uv[1];
  x[2] = h0.z + (float)uv[2]; x[3] = h0.w + (float)uv[3];
  x[4] = h1.x + (float)uv[4]; x[5] = h1.y + (float)uv[5];
  x[6] = h1.z + (float)uv[6]; x[7] = h1.w + (float)uv[7];
  float sum = 0.f;
#pragma unroll
  for (int u = 0; u < 8; ++u) sum += x[u];
#pragma unroll
  for (int m = 32; m; m >>= 1) sum += __shfl_xor(sum, m);
  const float mean = sum * (1.f / 512.f);
  float vs = 0.f;
#pragma unroll
  for (int u = 0; u < 8; ++u) { float d0 = x[u] - mean; vs += d0 * d0; }
#pragma unroll
  for (int m = 32; m; m >>= 1) vs += __shfl_xor(vs, m);
  const float rstd = rsqrtf(vs * (1.f / 512.f) + 1e-5f);
  float4 g0 = *(const float4*)(g + c0);
  float4 g1 = *(const float4*)(g + c0 + 4);
  float4 b0 = *(const float4*)(bta + c0);
  float4 b1 = *(const float4*)(bta + c0 + 4);
  float4 o0, o1;
  o0.x = (x[0] - mean) * rstd * g0.x + b0.x;
  o0.y = (x[1] - mean) * rstd * g0.y + b0.y;
  o0.z = (x[2] - mean) * rstd * g0.z + b0.z;
  o0.w = (x[3] - mean) * rstd * g0.w + b0.w;
  o1.x = (x[4] - mean) * rstd * g1.x + b1.x;
  o1.y = (x[5] - mean) * rstd * g1.y + b1.y;
  o1.z = (x[6] - mean) * rstd * g1.z + b1.z;
  o1.w = (x[7] - mean) * rstd * g1.w + b1.w;
  *(float4*)(out + hb + c0) = o0;
  *(float4*)(out + hb + c0 + 4) = o1;
}

extern "C" void kernel_launch(void* const* d_in, const int* in_sizes, int n_in,
                              void* d_out, int out_size, void* d_ws, size_t ws_size,
                              hipStream_t stream)
{
  (void)in_sizes; (void)n_in; (void)out_size; (void)ws_size;
  const float* H      = (const float*)d_in[0];
  const int*  pred    = (const int*)d_in[1];
  const int*  maskp   = (const int*)d_in[2];
  const float* hin_w  = (const float*)d_in[3];
  const float* hin_b  = (const float*)d_in[4];
  const float* hout_w = (const float*)d_in[5];
  const float* hout_b = (const float*)d_in[6];
  const float* sin_w  = (const float*)d_in[7];
  const float* sin_b  = (const float*)d_in[8];
  const float* sout_w = (const float*)d_in[9];
  const float* sout_b = (const float*)d_in[10];
  const float* ch_w   = (const float*)d_in[11];
  const float* ch_b   = (const float*)d_in[12];
  const float* g_w    = (const float*)d_in[13];
  const float* g_b    = (const float*)d_in[14];
  const float* t_w    = (const float*)d_in[15];
  const float* t_b    = (const float*)d_in[16];
  const float* lng    = (const float*)d_in[17];
  const float* lnb    = (const float*)d_in[18];

  char* ws = (char*)d_ws;
  __hip_bfloat16* Wqkv  = (__hip_bfloat16*)(ws + 0);          // 3072x512
  __hip_bfloat16* Wch   = (__hip_bfloat16*)(ws + 3145728);    // 512x1024
  __hip_bfloat16* Wgt   = (__hip_bfloat16*)(ws + 4194304);    // 1024x2048 (interleaved)
  float* bias_qkv       = (float*)(ws + 8388608);             // 3072
  float* bias_gt        = (float*)(ws + 8400896);             // 1024
  float* fvec           = (float*)(ws + 8404992);             // 1024
  float* flags          = (float*)(ws + 8409088);             // 16384
  __hip_bfloat16* Hbf   = (__hip_bfloat16*)(ws + 8474624);    // 16384x512
  char* QKVr            = ws + 25251840;                      // big region
  __hip_bfloat16* QKV   = (__hip_bfloat16*)QKVr;              // 16384x3072
  __hip_bfloat16* Whin  = (__hip_bfloat16*)(QKVr + 0);        // 1024x512 (pre-QKV)
  __hip_bfloat16* Wsin  = (__hip_bfloat16*)(QKVr + 1048576);  // 1024x512
  __hip_bfloat16* WhoT  = (__hip_bfloat16*)(QKVr + 2097152);  // 512x512
  __hip_bfloat16* WsoT  = (__hip_bfloat16*)(QKVr + 2621440);  // 512x512
  __hip_bfloat16* CHM   = (__hip_bfloat16*)(QKVr + 0);           // 16384x512 (post-attn)
  __hip_bfloat16* U     = (__hip_bfloat16*)(QKVr + 16777216);    // 16384x512 bf16
  __hip_bfloat16* Cavg  = (__hip_bfloat16*)(QKVr + 50331648);    // 16384x512
  __hip_bfloat16* CM2   = (__hip_bfloat16*)(ws + 125915136);  // 16384x1024 [Ohead|Osib]

  hipFuncSetAttribute(reinterpret_cast<const void*>(gemm8_kernel<0>),
                      hipFuncAttributeMaxDynamicSharedMemorySize, 131072);
  hipFuncSetAttribute(reinterpret_cast<const void*>(gemm8_kernel<2>),
                      hipFuncAttributeMaxDynamicSharedMemorySize, 131072);

  // merged prep (conversions + gate/trans interleave + out-proj transpose)
  prep_kernel<<<20480, 256, 0, stream>>>(hin_w, sin_w, ch_w, H, Wqkv, Wch, Hbf,
                                         g_w, t_w, g_b, t_b, Wgt, Whin, Wsin, bias_gt,
                                         hout_w, sout_w, WhoT, WsoT);
  foldbias_kernel<<<4, 256, 0, stream>>>(Whin, Wsin, hout_b, sout_b, bias_gt, fvec);
  hipMemcpyAsync(bias_qkv, hin_b, 1536 * 4, hipMemcpyDeviceToDevice, stream);
  hipMemcpyAsync(bias_qkv + 1536, sin_b, 1536 * 4, hipMemcpyDeviceToDevice, stream);

  // weight folds: Wgt[:,1024:1536] = Whin @ WhoT^T ; Wgt[:,1536:2048] = Wsin @ WsoT^T
  gemm_kernel<0, true><<<dim3(4, 8), 256, 0, stream>>>(
      Whin, 512, Whin, 512, Whin, 512, 512, 512, WhoT, 512,
      (const float*)nullptr, (const float*)nullptr, (const float*)nullptr,
      (void*)(Wgt + 1024), 2048, 512);
  gemm_kernel<0, true><<<dim3(4, 8), 256, 0, stream>>>(
      Wsin, 512, Wsin, 512, Wsin, 512, 512, 512, WsoT, 512,
      (const float*)nullptr, (const float*)nullptr, (const float*)nullptr,
      (void*)(Wgt + 1536), 2048, 512);

  // fused QKV projection (8-wave 256x256 pipelined)
  gemm8_kernel<0><<<dim3(12, 64), 512, 131072, stream>>>(
      Hbf, 512, Hbf, 512, Hbf, 512, 512, 512, Wqkv, 512,
      bias_qkv, (const float*)nullptr, (const float*)nullptr,
      (void*)QKV, 3072, 512);

  // merged attention (head + sib) -> CM2 slices
  attn_kernel<<<2048, 256, 0, stream>>>(QKV, pred, maskp, CM2, flags);

  // child aggregation (bf16 input) + child message GEMM (QKV dead now)
  child_kernel<<<dim3(8, 128), 256, 0, stream>>>(Hbf, pred, maskp, Cavg);
  gemm_kernel<1, true><<<dim3(4, 128), 256, 0, stream>>>(
      Hbf, 512, Cavg, 512, Cavg, 512, 512, 1024, Wch, 1024,
      ch_b, (const float*)nullptr, (const float*)nullptr,
      (void*)CHM, 512, 1024);

  // fused gate/trans GEMM (8-wave pipelined) over virtual comb = [Hbf | CHM | CM2]
  gemm8_kernel<2><<<dim3(4, 64), 512, 131072, stream>>>(
      Hbf, 512, CHM, 512, CM2, 1024, 512, 1024, Wgt, 2048,
      bias_gt, fvec, flags, (void*)U, 512, 2048);

  // residual + layernorm -> d_out
  ln_kernel<<<16384, 64, 0, stream>>>(H, U, lng, lnb, (float*)d_out);
}